// Round 13
// baseline (332.333 us; speedup 1.0000x reference)
//
#include <hip/hip_runtime.h>
#include <stdint.h>

using u16 = unsigned short;
typedef __bf16 bf16x8 __attribute__((ext_vector_type(8)));
typedef float f32x4 __attribute__((ext_vector_type(4)));

__device__ __forceinline__ u16 f2bf(float f) {
  union { float f; uint32_t u; } v; v.f = f;
  uint32_t r = v.u + 0x7fffu + ((v.u >> 16) & 1u);
  return (u16)(r >> 16);
}
__device__ __forceinline__ float bf2f(u16 h) {
  union { uint32_t u; float f; } v; v.u = ((uint32_t)h) << 16;
  return v.f;
}
__device__ __forceinline__ bf16x8 ldb8(const u16* p) {
  return *reinterpret_cast<const bf16x8*>(p);
}
__device__ __forceinline__ void gload_lds16(const void* g, void* l) {
  __builtin_amdgcn_global_load_lds(
      (const __attribute__((address_space(1))) void*)g,
      (__attribute__((address_space(3))) void*)l, 16, 0, 0);
}

// ---------------- elementwise convert f32 -> bf16 ----------------
__global__ __launch_bounds__(256) void convert_f32_bf16(
    const float* __restrict__ in, u16* __restrict__ out, int n4) {
  int idx = (blockIdx.x * 256 + threadIdx.x);
  if (idx >= n4) return;
  float4 v = *(const float4*)(in + (size_t)idx * 4);
  ushort4 o;
  o.x = f2bf(v.x); o.y = f2bf(v.y); o.z = f2bf(v.z); o.w = f2bf(v.w);
  *(ushort4*)(out + (size_t)idx * 4) = o;
}

// ---------------- transpose + convert: W (K x N f32) -> Wt (N x K bf16) ----
__global__ void transpose_convert(const float* __restrict__ W,
                                  u16* __restrict__ Wt, int K, int N) {
  __shared__ u16 tile[32][33];
  int n0 = blockIdx.x * 32, k0 = blockIdx.y * 32;
  int tx = threadIdx.x, ty = threadIdx.y;  // (32, 8)
#pragma unroll
  for (int i = 0; i < 32; i += 8)
    tile[ty + i][tx] = f2bf(W[(size_t)(k0 + ty + i) * N + n0 + tx]);
  __syncthreads();
#pragma unroll
  for (int i = 0; i < 32; i += 8)
    Wt[(size_t)(n0 + ty + i) * K + k0 + tx] = tile[tx][ty + i];
}

// ---------------- GEMM 128x128, depth-3 pipelined, XCD-swizzled -----------
// 4 LDS buffers; per K-step: counted vmcnt(8) (stage-t landed, stages
// t+1/t+2 stay in flight) -> one raw barrier (also fences consume(t-1)
// before STAGE(t+3) overwrites that buffer) -> issue STAGE(t+3) -> MFMA.
// Targets the small-grid latency-bound regime (1 block/CU: no implicit
// wave overlap; __syncthreads' vmcnt(0) drain would expose full HBM
// latency every step).
__global__ __launch_bounds__(256) void gemm_bt(
    const u16* __restrict__ A, const u16* __restrict__ Bt,
    u16* __restrict__ C, int M, int N, int K) {
  __shared__ __align__(16) u16 As[4][128 * 32];
  __shared__ __align__(16) u16 Bs[4][128 * 32];
  const int tid = threadIdx.x;
  const int w = tid >> 6, lane = tid & 63;
  const int wr = w >> 1, wc = w & 1;
  const int r16 = lane & 15, g = lane >> 4;
  const int nwg = gridDim.x * gridDim.y;
  const int idx = blockIdx.y * gridDim.x + blockIdx.x;
  const int swz = (idx & 7) * (nwg >> 3) + (idx >> 3);  // bijective, nwg%8==0
  const int m0 = (swz / gridDim.x) * 128, n0 = (swz % gridDim.x) * 128;
  const int ldrow = lane >> 2;
  const int ldk = (lane & 3) * 8;
  const int NT = K >> 5;

  f32x4 acc[4][4] = {};

#define GST128(tt)                                                        \
  do {                                                                    \
    const int kt_ = (tt) * 32, b_ = (tt) & 3;                             \
    _Pragma("unroll") for (int i = 0; i < 2; ++i) {                       \
      int chunk = w * 2 + i;                                              \
      int row = chunk * 16 + ldrow;                                       \
      gload_lds16(A + (size_t)(m0 + row) * K + kt_ + ldk,                 \
                  &As[b_][chunk * 512]);                                  \
      gload_lds16(Bt + (size_t)(n0 + row) * K + kt_ + ldk,                \
                  &Bs[b_][chunk * 512]);                                  \
    }                                                                     \
  } while (0)

  GST128(0);
  if (NT > 1) GST128(1);
  if (NT > 2) GST128(2);

  for (int t = 0; t < NT; ++t) {
    const int rem = NT - 1 - t;
    if (rem >= 2)      asm volatile("s_waitcnt vmcnt(8)" ::: "memory");
    else if (rem == 1) asm volatile("s_waitcnt vmcnt(4)" ::: "memory");
    else               asm volatile("s_waitcnt vmcnt(0)" ::: "memory");
    __builtin_amdgcn_s_barrier();
    __builtin_amdgcn_sched_barrier(0);
    if (t + 3 < NT) GST128(t + 3);

    const int b = t & 3;
    bf16x8 a[4], bb[4];
#pragma unroll
    for (int mt = 0; mt < 4; ++mt)
      a[mt] = ldb8(&As[b][(wr * 64 + mt * 16 + r16) * 32 + g * 8]);
#pragma unroll
    for (int nt = 0; nt < 4; ++nt)
      bb[nt] = ldb8(&Bs[b][(wc * 64 + nt * 16 + r16) * 32 + g * 8]);
#pragma unroll
    for (int mt = 0; mt < 4; ++mt)
#pragma unroll
      for (int nt = 0; nt < 4; ++nt)
        acc[mt][nt] = __builtin_amdgcn_mfma_f32_16x16x32_bf16(
            a[mt], bb[nt], acc[mt][nt], 0, 0, 0);
  }
#pragma unroll
  for (int mt = 0; mt < 4; ++mt)
#pragma unroll
    for (int nt = 0; nt < 4; ++nt)
#pragma unroll
      for (int r = 0; r < 4; ++r) {
        int row = m0 + wr * 64 + mt * 16 + g * 4 + r;
        int col = n0 + wc * 64 + nt * 16 + r16;
        C[(size_t)row * N + col] = f2bf(acc[mt][nt][r]);
      }
}

// ---------------- GEMM 64x128, depth-3 pipelined, XCD-swizzled ------------
__global__ __launch_bounds__(256) void gemm_bt64(
    const u16* __restrict__ A, const u16* __restrict__ Bt,
    u16* __restrict__ C, int M, int N, int K) {
  __shared__ __align__(16) u16 As[4][64 * 32];
  __shared__ __align__(16) u16 Bs[4][128 * 32];
  const int tid = threadIdx.x;
  const int w = tid >> 6, lane = tid & 63;
  const int wr = w >> 1, wc = w & 1;
  const int r16 = lane & 15, g = lane >> 4;
  const int nwg = gridDim.x * gridDim.y;
  const int idx = blockIdx.y * gridDim.x + blockIdx.x;
  const int swz = (idx & 7) * (nwg >> 3) + (idx >> 3);  // bijective, nwg%8==0
  const int m0 = (swz / gridDim.x) * 64, n0 = (swz % gridDim.x) * 128;
  const int ldrow = lane >> 2;
  const int ldk = (lane & 3) * 8;
  const int NT = K >> 5;

  f32x4 acc[2][4] = {};

#define GST64(tt)                                                         \
  do {                                                                    \
    const int kt_ = (tt) * 32, b_ = (tt) & 3;                             \
    _Pragma("unroll") for (int i = 0; i < 3; ++i) {                       \
      int chunk = w * 3 + i;                                              \
      if (chunk < 4) {                                                    \
        int row = chunk * 16 + ldrow;                                     \
        gload_lds16(A + (size_t)(m0 + row) * K + kt_ + ldk,               \
                    &As[b_][chunk * 512]);                                \
      } else {                                                            \
        int cb = chunk - 4;                                               \
        int row = cb * 16 + ldrow;                                        \
        gload_lds16(Bt + (size_t)(n0 + row) * K + kt_ + ldk,              \
                    &Bs[b_][cb * 512]);                                   \
      }                                                                   \
    }                                                                     \
  } while (0)

  GST64(0);
  if (NT > 1) GST64(1);
  if (NT > 2) GST64(2);

  for (int t = 0; t < NT; ++t) {
    const int rem = NT - 1 - t;
    if (rem >= 2)      asm volatile("s_waitcnt vmcnt(6)" ::: "memory");
    else if (rem == 1) asm volatile("s_waitcnt vmcnt(3)" ::: "memory");
    else               asm volatile("s_waitcnt vmcnt(0)" ::: "memory");
    __builtin_amdgcn_s_barrier();
    __builtin_amdgcn_sched_barrier(0);
    if (t + 3 < NT) GST64(t + 3);

    const int b = t & 3;
    bf16x8 a[2], bb[4];
#pragma unroll
    for (int mt = 0; mt < 2; ++mt)
      a[mt] = ldb8(&As[b][(wr * 32 + mt * 16 + r16) * 32 + g * 8]);
#pragma unroll
    for (int nt = 0; nt < 4; ++nt)
      bb[nt] = ldb8(&Bs[b][(wc * 64 + nt * 16 + r16) * 32 + g * 8]);
#pragma unroll
    for (int mt = 0; mt < 2; ++mt)
#pragma unroll
      for (int nt = 0; nt < 4; ++nt)
        acc[mt][nt] = __builtin_amdgcn_mfma_f32_16x16x32_bf16(
            a[mt], bb[nt], acc[mt][nt], 0, 0, 0);
  }
#pragma unroll
  for (int mt = 0; mt < 2; ++mt)
#pragma unroll
    for (int nt = 0; nt < 4; ++nt)
#pragma unroll
      for (int r = 0; r < 4; ++r) {
        int row = m0 + wr * 32 + mt * 16 + g * 4 + r;
        int col = n0 + wc * 64 + nt * 16 + r16;
        C[(size_t)row * N + col] = f2bf(acc[mt][nt][r]);
      }
}

// ---------------- RoPE + split + coalesced V-transpose --------------------
__global__ __launch_bounds__(256) void rope_kernel(
    const u16* __restrict__ qkv, const float* __restrict__ cosb,
    const float* __restrict__ sinb, u16* __restrict__ qb,
    u16* __restrict__ kb, u16* __restrict__ vt) {
  const int h = blockIdx.y;
  const int s0 = blockIdx.x * 32;
  const int t = threadIdx.x;
  const int d = t & 63;
  const int sgrp = t >> 6;  // 0..3

  __shared__ u16 vs[64][33];

#pragma unroll
  for (int it = 0; it < 8; ++it) {
    const int sl = it * 4 + sgrp;
    const int s = s0 + sl;
    const size_t base = (size_t)s * 3072;
    float q = bf2f(qkv[base + h * 64 + d]);
    float k = bf2f(qkv[base + (16 + h) * 64 + d]);
    float v = bf2f(qkv[base + (32 + h) * 64 + d]);
    float c = cosb[s * 64 + d], sn = sinb[s * 64 + d];
    int dp = d < 32 ? d + 32 : d - 32;
    float sgn = d < 32 ? -1.f : 1.f;
    float qr = bf2f(qkv[base + h * 64 + dp]);
    float kr = bf2f(qkv[base + (16 + h) * 64 + dp]);
    float qo = q * c + sgn * qr * sn;
    float ko = k * c + sgn * kr * sn;
    size_t o = ((size_t)h * 2048 + s) * 64 + d;
    qb[o] = f2bf(qo * 0.125f);  // fold score scale 1/sqrt(64)
    kb[o] = f2bf(ko);
    vs[d][sl] = f2bf(v);
  }
  __syncthreads();

  const int d2 = t >> 2;
  const int sc8 = (t & 3) * 8;
  ushort4 o0, o1;
  o0.x = vs[d2][sc8 + 0]; o0.y = vs[d2][sc8 + 1];
  o0.z = vs[d2][sc8 + 2]; o0.w = vs[d2][sc8 + 3];
  o1.x = vs[d2][sc8 + 4]; o1.y = vs[d2][sc8 + 5];
  o1.z = vs[d2][sc8 + 6]; o1.w = vs[d2][sc8 + 7];
  u16* dst = vt + ((size_t)h * 64 + d2) * 2048 + s0 + sc8;
  *(ushort4*)(dst) = o0;
  *(ushort4*)(dst + 4) = o1;
}

// ---------------- flash attention (R9-exact) ------------------------------
__global__ __launch_bounds__(256, 2) void attn_kernel(
    const u16* __restrict__ qb, const u16* __restrict__ kb,
    const u16* __restrict__ vt, const float* __restrict__ bias,
    u16* __restrict__ attnb) {
  const int bid = blockIdx.x;
  const int swz = (bid & 7) * 64 + (bid >> 3);
  const int h = swz >> 5;
  const int qt = swz & 31;
  const int tid = threadIdx.x;
  const int w = tid >> 6;
  const int lane = tid & 63;
  const int r16 = lane & 15, g = lane >> 4;

  __shared__ __align__(16) u16 P_lds[4][16 * 32];
  __shared__ float acc_s[4][16][64];
  __shared__ float m_s[4][16], l_s[4][16];

  bf16x8 qf0[4], qf1[4];
#pragma unroll
  for (int st = 0; st < 4; ++st) {
    const u16* qrow =
        qb + ((size_t)h * 2048 + qt * 64 + st * 16 + r16) * 64;
    qf0[st] = ldb8(qrow + g * 8);
    qf1[st] = ldb8(qrow + 32 + g * 8);
  }

  f32x4 acc[4][4] = {};
  float m[4][4], lsum[4][4];
#pragma unroll
  for (int st = 0; st < 4; ++st)
#pragma unroll
    for (int r = 0; r < 4; ++r) { m[st][r] = -1e30f; lsum[st][r] = 0.f; }

  const float* bbase = bias + ((size_t)h * 2048 + qt * 64) * 2048;

  const int kv0 = w * 512, kv1 = kv0 + 512;
  for (int kt = kv0; kt < kv1; kt += 32) {
    bf16x8 ka[2], kc[2];
#pragma unroll
    for (int c = 0; c < 2; ++c) {
      const u16* krow = kb + ((size_t)h * 2048 + kt + c * 16 + r16) * 64;
      ka[c] = ldb8(krow + g * 8);
      kc[c] = ldb8(krow + 32 + g * 8);
    }
    bf16x8 vf[4];
#pragma unroll
    for (int nt = 0; nt < 4; ++nt)
      vf[nt] =
          ldb8(vt + ((size_t)h * 64 + nt * 16 + r16) * 2048 + kt + g * 8);

#pragma unroll
    for (int st = 0; st < 4; ++st) {
      float bv[2][4];
#pragma unroll
      for (int c = 0; c < 2; ++c)
#pragma unroll
        for (int r = 0; r < 4; ++r)
          bv[c][r] = bbase[(size_t)(st * 16 + g * 4 + r) * 2048 + kt +
                           c * 16 + r16];

      f32x4 sc[2];
#pragma unroll
      for (int c = 0; c < 2; ++c) {
        f32x4 z = {0.f, 0.f, 0.f, 0.f};
        f32x4 t =
            __builtin_amdgcn_mfma_f32_16x16x32_bf16(qf0[st], ka[c], z, 0, 0, 0);
        sc[c] =
            __builtin_amdgcn_mfma_f32_16x16x32_bf16(qf1[st], kc[c], t, 0, 0, 0);
      }
#pragma unroll
      for (int c = 0; c < 2; ++c)
#pragma unroll
        for (int r = 0; r < 4; ++r)
          sc[c][r] += bv[c][r];

      float mnew[4], rs[4];
#pragma unroll
      for (int r = 0; r < 4; ++r) {
        float t = fmaxf(sc[0][r], sc[1][r]);
        t = fmaxf(t, __shfl_xor(t, 1));
        t = fmaxf(t, __shfl_xor(t, 2));
        t = fmaxf(t, __shfl_xor(t, 4));
        t = fmaxf(t, __shfl_xor(t, 8));
        mnew[r] = fmaxf(m[st][r], t);
      }
#pragma unroll
      for (int r = 0; r < 4; ++r) {
        float p0 = __expf(sc[0][r] - mnew[r]);
        float p1 = __expf(sc[1][r] - mnew[r]);
        sc[0][r] = p0; sc[1][r] = p1;
        float t = p0 + p1;
        t += __shfl_xor(t, 1);
        t += __shfl_xor(t, 2);
        t += __shfl_xor(t, 4);
        t += __shfl_xor(t, 8);
        rs[r] = t;
        float alpha = __expf(m[st][r] - mnew[r]);
        lsum[st][r] = lsum[st][r] * alpha + rs[r];
        m[st][r] = mnew[r];
#pragma unroll
        for (int nt = 0; nt < 4; ++nt) acc[st][nt][r] *= alpha;
      }
#pragma unroll
      for (int c = 0; c < 2; ++c)
#pragma unroll
        for (int r = 0; r < 4; ++r)
          P_lds[w][(g * 4 + r) * 32 + c * 16 + r16] = f2bf(sc[c][r]);
      bf16x8 pf = ldb8(&P_lds[w][r16 * 32 + g * 8]);
#pragma unroll
      for (int nt = 0; nt < 4; ++nt)
        acc[st][nt] = __builtin_amdgcn_mfma_f32_16x16x32_bf16(
            pf, vf[nt], acc[st][nt], 0, 0, 0);
    }
  }

#pragma unroll
  for (int st = 0; st < 4; ++st) {
    __syncthreads();
#pragma unroll
    for (int nt = 0; nt < 4; ++nt)
#pragma unroll
      for (int r = 0; r < 4; ++r)
        acc_s[w][g * 4 + r][nt * 16 + r16] = acc[st][nt][r];
    if (r16 == 0) {
#pragma unroll
      for (int r = 0; r < 4; ++r) {
        m_s[w][g * 4 + r] = m[st][r];
        l_s[w][g * 4 + r] = lsum[st][r];
      }
    }
    __syncthreads();

    const int row = tid >> 4;
    const int col4 = (tid & 15) * 4;
    float m0v = m_s[0][row], m1v = m_s[1][row], m2v = m_s[2][row],
          m3v = m_s[3][row];
    float mm = fmaxf(fmaxf(m0v, m1v), fmaxf(m2v, m3v));
    float s0 = __expf(m0v - mm), s1 = __expf(m1v - mm);
    float s2 = __expf(m2v - mm), s3 = __expf(m3v - mm);
    float ltot = l_s[0][row] * s0 + l_s[1][row] * s1 + l_s[2][row] * s2 +
                 l_s[3][row] * s3;
    float inv = 1.f / ltot;
    ushort4 ov;
    u16* outp =
        attnb + (size_t)(qt * 64 + st * 16 + row) * 1024 + h * 64 + col4;
#pragma unroll
    for (int j = 0; j < 4; ++j) {
      float v = acc_s[0][row][col4 + j] * s0 + acc_s[1][row][col4 + j] * s1 +
                acc_s[2][row][col4 + j] * s2 + acc_s[3][row][col4 + j] * s3;
      ((u16*)&ov)[j] = f2bf(v * inv);
    }
    *(ushort4*)outp = ov;
  }
}

// ---------------- residual add + RMSNorm ----------------------------------
__global__ __launch_bounds__(256) void addnorm_kernel(
    const float* __restrict__ resid, const u16* __restrict__ delta,
    float* __restrict__ outf, u16* __restrict__ outb) {
  int row = blockIdx.x, tid = threadIdx.x;
  size_t base = (size_t)row * 1024 + tid * 4;
  float4 rv = *(const float4*)(resid + base);
  ushort4 dv = *(const ushort4*)(delta + base);
  float x0 = rv.x + bf2f(dv.x);
  float x1 = rv.y + bf2f(dv.y);
  float x2 = rv.z + bf2f(dv.z);
  float x3 = rv.w + bf2f(dv.w);
  float ss = x0 * x0 + x1 * x1 + x2 * x2 + x3 * x3;
#pragma unroll
  for (int sh = 32; sh >= 1; sh >>= 1) ss += __shfl_xor(ss, sh);
  __shared__ float red[4];
  if ((tid & 63) == 0) red[tid >> 6] = ss;
  __syncthreads();
  float tot = red[0] + red[1] + red[2] + red[3];
  float rstd = rsqrtf(tot * (1.0f / 1024.0f) + 1e-5f);
  float4 ov;
  ov.x = x0 * rstd; ov.y = x1 * rstd; ov.z = x2 * rstd; ov.w = x3 * rstd;
  *(float4*)(outf + base) = ov;
  if (outb) {
    ushort4 ob;
    ob.x = f2bf(ov.x); ob.y = f2bf(ov.y); ob.z = f2bf(ov.z); ob.w = f2bf(ov.w);
    *(ushort4*)(outb + base) = ob;
  }
}

// ---------------- SwiGLU ---------------------------------------------------
__global__ __launch_bounds__(256) void swiglu_kernel(
    const u16* __restrict__ gu, u16* __restrict__ hb) {
  int s = blockIdx.x, tid = threadIdx.x;
  const u16* grow = gu + (size_t)s * 5632;
  u16* hrow = hb + (size_t)s * 2816;
  for (int j = tid * 4; j < 2816; j += 1024) {
    ushort4 gv = *(const ushort4*)(grow + j);
    ushort4 uv = *(const ushort4*)(grow + 2816 + j);
    float g0 = bf2f(gv.x), g1 = bf2f(gv.y), g2 = bf2f(gv.z), g3 = bf2f(gv.w);
    float u0 = bf2f(uv.x), u1 = bf2f(uv.y), u2 = bf2f(uv.z), u3 = bf2f(uv.w);
    ushort4 ho;
    ho.x = f2bf(g0 / (1.f + __expf(-g0)) * u0);
    ho.y = f2bf(g1 / (1.f + __expf(-g1)) * u1);
    ho.z = f2bf(g2 / (1.f + __expf(-g2)) * u2);
    ho.w = f2bf(g3 / (1.f + __expf(-g3)) * u3);
    *(ushort4*)(hrow + j) = ho;
  }
}

extern "C" void kernel_launch(void* const* d_in, const int* in_sizes, int n_in,
                              void* d_out, int out_size, void* d_ws,
                              size_t ws_size, hipStream_t stream) {
  (void)in_sizes; (void)n_in; (void)out_size; (void)ws_size;
  const float* cosb  = (const float*)d_in[0];
  const float* sinb  = (const float*)d_in[1];
  const float* hidden = (const float*)d_in[2];
  const float* bias  = (const float*)d_in[3];
  const float* w_qkv = (const float*)d_in[4];
  const float* w_o   = (const float*)d_in[5];
  const float* w_gu  = (const float*)d_in[6];
  const float* w_down = (const float*)d_in[7];
  float* out = (float*)d_out;

  char* p = (char*)d_ws;
  auto alloc = [&](size_t bytes) {
    void* r = (void*)p;
    p += (bytes + 255) & ~(size_t)255;
    return r;
  };
  u16* wqkv_t = (u16*)alloc((size_t)3072 * 1024 * 2);
  u16* wo_t   = (u16*)alloc((size_t)1024 * 1024 * 2);
  u16* wgu_t  = (u16*)alloc((size_t)5632 * 1024 * 2);
  u16* wd_t   = (u16*)alloc((size_t)1024 * 2816 * 2);
  u16* xb     = (u16*)alloc((size_t)2048 * 1024 * 2);
  u16* qkvb   = (u16*)alloc((size_t)2048 * 3072 * 2);
  u16* qb     = (u16*)alloc((size_t)16 * 2048 * 64 * 2);
  u16* kb     = (u16*)alloc((size_t)16 * 2048 * 64 * 2);
  u16* vt     = (u16*)alloc((size_t)16 * 2048 * 64 * 2);
  u16* attnb  = (u16*)alloc((size_t)2048 * 1024 * 2);
  u16* ob     = (u16*)alloc((size_t)2048 * 1024 * 2);
  float* x1f  = (float*)alloc((size_t)2048 * 1024 * 4);
  u16* x1b    = (u16*)alloc((size_t)2048 * 1024 * 2);
  u16* gub    = (u16*)alloc((size_t)2048 * 5632 * 2);
  u16* hb     = (u16*)alloc((size_t)2048 * 2816 * 2);
  u16* mlpb   = (u16*)alloc((size_t)2048 * 1024 * 2);

  dim3 tb(32, 8);
  convert_f32_bf16<<<2048, 256, 0, stream>>>(hidden, xb, 2048 * 1024 / 4);
  transpose_convert<<<dim3(3072 / 32, 1024 / 32), tb, 0, stream>>>(w_qkv, wqkv_t, 1024, 3072);
  transpose_convert<<<dim3(1024 / 32, 1024 / 32), tb, 0, stream>>>(w_o, wo_t, 1024, 1024);
  transpose_convert<<<dim3(5632 / 32, 1024 / 32), tb, 0, stream>>>(w_gu, wgu_t, 1024, 5632);
  transpose_convert<<<dim3(1024 / 32, 2816 / 32), tb, 0, stream>>>(w_down, wd_t, 2816, 1024);

  gemm_bt<<<dim3(3072 / 128, 2048 / 128), 256, 0, stream>>>(xb, wqkv_t, qkvb, 2048, 3072, 1024);
  rope_kernel<<<dim3(64, 16), 256, 0, stream>>>(qkvb, cosb, sinb, qb, kb, vt);
  attn_kernel<<<512, 256, 0, stream>>>(qb, kb, vt, bias, attnb);
  gemm_bt64<<<dim3(1024 / 128, 2048 / 64), 256, 0, stream>>>(attnb, wo_t, ob, 2048, 1024, 1024);
  addnorm_kernel<<<2048, 256, 0, stream>>>(hidden, ob, x1f, x1b);
  gemm_bt<<<dim3(5632 / 128, 2048 / 128), 256, 0, stream>>>(x1b, wgu_t, gub, 2048, 5632, 1024);
  swiglu_kernel<<<2048, 256, 0, stream>>>(gub, hb);
  gemm_bt64<<<dim3(1024 / 128, 2048 / 64), 256, 0, stream>>>(hb, wd_t, mlpb, 2048, 1024, 2816);
  addnorm_kernel<<<2048, 256, 0, stream>>>(x1f, mlpb, out, nullptr);
}

// Round 14
// 309.879 us; speedup vs baseline: 1.0725x; 1.0725x over previous
//
#include <hip/hip_runtime.h>
#include <stdint.h>

using u16 = unsigned short;
typedef __bf16 bf16x8 __attribute__((ext_vector_type(8)));
typedef float f32x4 __attribute__((ext_vector_type(4)));

__device__ __forceinline__ u16 f2bf(float f) {
  union { float f; uint32_t u; } v; v.f = f;
  uint32_t r = v.u + 0x7fffu + ((v.u >> 16) & 1u);
  return (u16)(r >> 16);
}
__device__ __forceinline__ float bf2f(u16 h) {
  union { uint32_t u; float f; } v; v.u = ((uint32_t)h) << 16;
  return v.f;
}
__device__ __forceinline__ bf16x8 ldb8(const u16* p) {
  return *reinterpret_cast<const bf16x8*>(p);
}
__device__ __forceinline__ void gload_lds16(const void* g, void* l) {
  __builtin_amdgcn_global_load_lds(
      (const __attribute__((address_space(1))) void*)g,
      (__attribute__((address_space(3))) void*)l, 16, 0, 0);
}

// ---------------- fused prep: f32->bf16 convert + 4 weight transposes -----
// One launch replaces 5. Jobs partitioned by blockIdx.x:
//   [0,3072)      wqkv transpose  (N=3072, K=1024)
//   [3072,4096)   wo transpose    (N=1024, K=1024)
//   [4096,9728)   wgu transpose   (N=5632, K=1024), INTERLEAVED perm:
//                 wgu_t[n][k] = w_gu[k][ n even ? n/2 : 2816+n/2 ]
//                 -> every 128-col GEMM tile holds (gate,up) pairs adjacent
//   [9728,12544)  wd transpose    (N=1024, K=2816)
//   [12544,14592) hidden f32 -> xb bf16 (2048*1024 elems)
__global__ __launch_bounds__(256) void prep_kernel(
    const float* __restrict__ w_qkv, const float* __restrict__ w_o,
    const float* __restrict__ w_gu, const float* __restrict__ w_down,
    const float* __restrict__ hidden, u16* __restrict__ wqkv_t,
    u16* __restrict__ wo_t, u16* __restrict__ wgu_t, u16* __restrict__ wd_t,
    u16* __restrict__ xb) {
  const int b = blockIdx.x;
  const int t = threadIdx.x;

  if (b >= 12544) {  // convert job
    int idx = (b - 12544) * 256 + t;
    float4 v = *(const float4*)(hidden + (size_t)idx * 4);
    ushort4 o;
    o.x = f2bf(v.x); o.y = f2bf(v.y); o.z = f2bf(v.z); o.w = f2bf(v.w);
    *(ushort4*)(xb + (size_t)idx * 4) = o;
    return;
  }

  const float* W;
  u16* Wt;
  int N, K, lb;
  bool perm = false;
  if (b < 3072)      { W = w_qkv; Wt = wqkv_t; N = 3072; K = 1024; lb = b; }
  else if (b < 4096) { W = w_o;   Wt = wo_t;   N = 1024; K = 1024; lb = b - 3072; }
  else if (b < 9728) { W = w_gu;  Wt = wgu_t;  N = 5632; K = 1024; lb = b - 4096; perm = true; }
  else               { W = w_down; Wt = wd_t;  N = 1024; K = 2816; lb = b - 9728; }

  const int nx = N >> 5;
  const int n0 = (lb % nx) * 32, k0 = (lb / nx) * 32;
  const int tx = t & 31, ty = t >> 5;  // (32, 8)

  __shared__ u16 tile[32][33];
  const int nc = n0 + tx;
  const int src_col = perm ? (((nc & 1) == 0) ? (nc >> 1) : 2816 + (nc >> 1))
                           : nc;
#pragma unroll
  for (int i = 0; i < 32; i += 8)
    tile[ty + i][tx] = f2bf(W[(size_t)(k0 + ty + i) * N + src_col]);
  __syncthreads();
#pragma unroll
  for (int i = 0; i < 32; i += 8)
    Wt[(size_t)(n0 + ty + i) * K + k0 + tx] = tile[tx][ty + i];
}

// ---------------- GEMM 128x128: C = A * Bt^T (R12-exact, XCD-swizzled) ----
__global__ __launch_bounds__(256) void gemm_bt(
    const u16* __restrict__ A, const u16* __restrict__ Bt,
    u16* __restrict__ C, int M, int N, int K) {
  __shared__ __align__(16) u16 As[128 * 32];
  __shared__ __align__(16) u16 Bs[128 * 32];
  const int tid = threadIdx.x;
  const int w = tid >> 6, lane = tid & 63;
  const int wr = w >> 1, wc = w & 1;
  const int r16 = lane & 15, g = lane >> 4;
  const int nwg = gridDim.x * gridDim.y;
  const int idx = blockIdx.y * gridDim.x + blockIdx.x;
  const int swz = (idx & 7) * (nwg >> 3) + (idx >> 3);  // bijective, nwg%8==0
  const int m0 = (swz / gridDim.x) * 128, n0 = (swz % gridDim.x) * 128;
  const int ldrow = lane >> 2;
  const int ldk = (lane & 3) * 8;

  f32x4 acc[4][4] = {};

  for (int kt = 0; kt < K; kt += 32) {
#pragma unroll
    for (int i = 0; i < 2; ++i) {
      int chunk = w * 2 + i;
      int row = chunk * 16 + ldrow;
      gload_lds16(A + (size_t)(m0 + row) * K + kt + ldk, &As[chunk * 512]);
      gload_lds16(Bt + (size_t)(n0 + row) * K + kt + ldk, &Bs[chunk * 512]);
    }
    __syncthreads();
    bf16x8 a[4], b[4];
#pragma unroll
    for (int mt = 0; mt < 4; ++mt)
      a[mt] = ldb8(&As[(wr * 64 + mt * 16 + r16) * 32 + g * 8]);
#pragma unroll
    for (int nt = 0; nt < 4; ++nt)
      b[nt] = ldb8(&Bs[(wc * 64 + nt * 16 + r16) * 32 + g * 8]);
#pragma unroll
    for (int mt = 0; mt < 4; ++mt)
#pragma unroll
      for (int nt = 0; nt < 4; ++nt)
        acc[mt][nt] = __builtin_amdgcn_mfma_f32_16x16x32_bf16(
            a[mt], b[nt], acc[mt][nt], 0, 0, 0);
    __syncthreads();
  }
#pragma unroll
  for (int mt = 0; mt < 4; ++mt)
#pragma unroll
    for (int nt = 0; nt < 4; ++nt)
#pragma unroll
      for (int r = 0; r < 4; ++r) {
        int row = m0 + wr * 64 + mt * 16 + g * 4 + r;
        int col = n0 + wc * 64 + nt * 16 + r16;
        C[(size_t)row * N + col] = f2bf(acc[mt][nt][r]);
      }
}

// ---------------- GEMM 128x128 + fused SwiGLU epilogue --------------------
// Identical main loop to gemm_bt; Bt is the INTERLEAVED wgu_t (col 2i =
// gate_i, col 2i+1 = up_i). Epilogue pairs adjacent lanes via shfl_xor(1):
// even lane holds gate, odd holds up; even lanes write silu(g)*u to
// Hb[row][col/2] (ld 2816). Saves the 23MB gub write + 23MB read + launch.
__global__ __launch_bounds__(256) void gemm_bt_swiglu(
    const u16* __restrict__ A, const u16* __restrict__ Bt,
    u16* __restrict__ Hb, int M, int N, int K) {
  __shared__ __align__(16) u16 As[128 * 32];
  __shared__ __align__(16) u16 Bs[128 * 32];
  const int tid = threadIdx.x;
  const int w = tid >> 6, lane = tid & 63;
  const int wr = w >> 1, wc = w & 1;
  const int r16 = lane & 15, g = lane >> 4;
  const int nwg = gridDim.x * gridDim.y;
  const int idx = blockIdx.y * gridDim.x + blockIdx.x;
  const int swz = (idx & 7) * (nwg >> 3) + (idx >> 3);
  const int m0 = (swz / gridDim.x) * 128, n0 = (swz % gridDim.x) * 128;
  const int ldrow = lane >> 2;
  const int ldk = (lane & 3) * 8;

  f32x4 acc[4][4] = {};

  for (int kt = 0; kt < K; kt += 32) {
#pragma unroll
    for (int i = 0; i < 2; ++i) {
      int chunk = w * 2 + i;
      int row = chunk * 16 + ldrow;
      gload_lds16(A + (size_t)(m0 + row) * K + kt + ldk, &As[chunk * 512]);
      gload_lds16(Bt + (size_t)(n0 + row) * K + kt + ldk, &Bs[chunk * 512]);
    }
    __syncthreads();
    bf16x8 a[4], b[4];
#pragma unroll
    for (int mt = 0; mt < 4; ++mt)
      a[mt] = ldb8(&As[(wr * 64 + mt * 16 + r16) * 32 + g * 8]);
#pragma unroll
    for (int nt = 0; nt < 4; ++nt)
      b[nt] = ldb8(&Bs[(wc * 64 + nt * 16 + r16) * 32 + g * 8]);
#pragma unroll
    for (int mt = 0; mt < 4; ++mt)
#pragma unroll
      for (int nt = 0; nt < 4; ++nt)
        acc[mt][nt] = __builtin_amdgcn_mfma_f32_16x16x32_bf16(
            a[mt], b[nt], acc[mt][nt], 0, 0, 0);
    __syncthreads();
  }
#pragma unroll
  for (int mt = 0; mt < 4; ++mt)
#pragma unroll
    for (int nt = 0; nt < 4; ++nt)
#pragma unroll
      for (int r = 0; r < 4; ++r) {
        float val = acc[mt][nt][r];
        float other = __shfl_xor(val, 1);  // all lanes participate
        if ((r16 & 1) == 0) {
          float o = val / (1.f + __expf(-val)) * other;  // silu(gate)*up
          int row = m0 + wr * 64 + mt * 16 + g * 4 + r;
          int col = n0 + wc * 64 + nt * 16 + r16;
          Hb[(size_t)row * 2816 + (col >> 1)] = f2bf(o);
        }
      }
}

// ---------------- GEMM 64x128 (R12-exact, XCD-swizzled) -------------------
__global__ __launch_bounds__(256) void gemm_bt64(
    const u16* __restrict__ A, const u16* __restrict__ Bt,
    u16* __restrict__ C, int M, int N, int K) {
  __shared__ __align__(16) u16 As[64 * 32];
  __shared__ __align__(16) u16 Bs[128 * 32];
  const int tid = threadIdx.x;
  const int w = tid >> 6, lane = tid & 63;
  const int wr = w >> 1, wc = w & 1;
  const int r16 = lane & 15, g = lane >> 4;
  const int nwg = gridDim.x * gridDim.y;
  const int idx = blockIdx.y * gridDim.x + blockIdx.x;
  const int swz = (idx & 7) * (nwg >> 3) + (idx >> 3);  // bijective, nwg%8==0
  const int m0 = (swz / gridDim.x) * 64, n0 = (swz % gridDim.x) * 128;
  const int ldrow = lane >> 2;
  const int ldk = (lane & 3) * 8;

  f32x4 acc[2][4] = {};

  for (int kt = 0; kt < K; kt += 32) {
#pragma unroll
    for (int i = 0; i < 3; ++i) {
      int chunk = w * 3 + i;  // 0..11: 0-3 -> A, 4-11 -> B
      if (chunk < 4) {
        int row = chunk * 16 + ldrow;
        gload_lds16(A + (size_t)(m0 + row) * K + kt + ldk, &As[chunk * 512]);
      } else {
        int cb = chunk - 4;
        int row = cb * 16 + ldrow;
        gload_lds16(Bt + (size_t)(n0 + row) * K + kt + ldk, &Bs[cb * 512]);
      }
    }
    __syncthreads();
    bf16x8 a[2], b[4];
#pragma unroll
    for (int mt = 0; mt < 2; ++mt)
      a[mt] = ldb8(&As[(wr * 32 + mt * 16 + r16) * 32 + g * 8]);
#pragma unroll
    for (int nt = 0; nt < 4; ++nt)
      b[nt] = ldb8(&Bs[(wc * 64 + nt * 16 + r16) * 32 + g * 8]);
#pragma unroll
    for (int mt = 0; mt < 2; ++mt)
#pragma unroll
      for (int nt = 0; nt < 4; ++nt)
        acc[mt][nt] = __builtin_amdgcn_mfma_f32_16x16x32_bf16(
            a[mt], b[nt], acc[mt][nt], 0, 0, 0);
    __syncthreads();
  }
#pragma unroll
  for (int mt = 0; mt < 2; ++mt)
#pragma unroll
    for (int nt = 0; nt < 4; ++nt)
#pragma unroll
      for (int r = 0; r < 4; ++r) {
        int row = m0 + wr * 32 + mt * 16 + g * 4 + r;
        int col = n0 + wc * 64 + nt * 16 + r16;
        C[(size_t)row * N + col] = f2bf(acc[mt][nt][r]);
      }
}

// ---------------- RoPE + split + coalesced V-transpose --------------------
__global__ __launch_bounds__(256) void rope_kernel(
    const u16* __restrict__ qkv, const float* __restrict__ cosb,
    const float* __restrict__ sinb, u16* __restrict__ qb,
    u16* __restrict__ kb, u16* __restrict__ vt) {
  const int h = blockIdx.y;
  const int s0 = blockIdx.x * 32;
  const int t = threadIdx.x;
  const int d = t & 63;
  const int sgrp = t >> 6;  // 0..3

  __shared__ u16 vs[64][33];

#pragma unroll
  for (int it = 0; it < 8; ++it) {
    const int sl = it * 4 + sgrp;
    const int s = s0 + sl;
    const size_t base = (size_t)s * 3072;
    float q = bf2f(qkv[base + h * 64 + d]);
    float k = bf2f(qkv[base + (16 + h) * 64 + d]);
    float v = bf2f(qkv[base + (32 + h) * 64 + d]);
    float c = cosb[s * 64 + d], sn = sinb[s * 64 + d];
    int dp = d < 32 ? d + 32 : d - 32;
    float sgn = d < 32 ? -1.f : 1.f;
    float qr = bf2f(qkv[base + h * 64 + dp]);
    float kr = bf2f(qkv[base + (16 + h) * 64 + dp]);
    float qo = q * c + sgn * qr * sn;
    float ko = k * c + sgn * kr * sn;
    size_t o = ((size_t)h * 2048 + s) * 64 + d;
    qb[o] = f2bf(qo * 0.125f);  // fold score scale 1/sqrt(64)
    kb[o] = f2bf(ko);
    vs[d][sl] = f2bf(v);
  }
  __syncthreads();

  const int d2 = t >> 2;
  const int sc8 = (t & 3) * 8;
  ushort4 o0, o1;
  o0.x = vs[d2][sc8 + 0]; o0.y = vs[d2][sc8 + 1];
  o0.z = vs[d2][sc8 + 2]; o0.w = vs[d2][sc8 + 3];
  o1.x = vs[d2][sc8 + 4]; o1.y = vs[d2][sc8 + 5];
  o1.z = vs[d2][sc8 + 6]; o1.w = vs[d2][sc8 + 7];
  u16* dst = vt + ((size_t)h * 64 + d2) * 2048 + s0 + sc8;
  *(ushort4*)(dst) = o0;
  *(ushort4*)(dst + 4) = o1;
}

// ---------------- flash attention (R9-exact) ------------------------------
__global__ __launch_bounds__(256, 2) void attn_kernel(
    const u16* __restrict__ qb, const u16* __restrict__ kb,
    const u16* __restrict__ vt, const float* __restrict__ bias,
    u16* __restrict__ attnb) {
  const int bid = blockIdx.x;
  const int swz = (bid & 7) * 64 + (bid >> 3);
  const int h = swz >> 5;
  const int qt = swz & 31;
  const int tid = threadIdx.x;
  const int w = tid >> 6;
  const int lane = tid & 63;
  const int r16 = lane & 15, g = lane >> 4;

  __shared__ __align__(16) u16 P_lds[4][16 * 32];
  __shared__ float acc_s[4][16][64];
  __shared__ float m_s[4][16], l_s[4][16];

  bf16x8 qf0[4], qf1[4];
#pragma unroll
  for (int st = 0; st < 4; ++st) {
    const u16* qrow =
        qb + ((size_t)h * 2048 + qt * 64 + st * 16 + r16) * 64;
    qf0[st] = ldb8(qrow + g * 8);
    qf1[st] = ldb8(qrow + 32 + g * 8);
  }

  f32x4 acc[4][4] = {};
  float m[4][4], lsum[4][4];
#pragma unroll
  for (int st = 0; st < 4; ++st)
#pragma unroll
    for (int r = 0; r < 4; ++r) { m[st][r] = -1e30f; lsum[st][r] = 0.f; }

  const float* bbase = bias + ((size_t)h * 2048 + qt * 64) * 2048;

  const int kv0 = w * 512, kv1 = kv0 + 512;
  for (int kt = kv0; kt < kv1; kt += 32) {
    bf16x8 ka[2], kc[2];
#pragma unroll
    for (int c = 0; c < 2; ++c) {
      const u16* krow = kb + ((size_t)h * 2048 + kt + c * 16 + r16) * 64;
      ka[c] = ldb8(krow + g * 8);
      kc[c] = ldb8(krow + 32 + g * 8);
    }
    bf16x8 vf[4];
#pragma unroll
    for (int nt = 0; nt < 4; ++nt)
      vf[nt] =
          ldb8(vt + ((size_t)h * 64 + nt * 16 + r16) * 2048 + kt + g * 8);

#pragma unroll
    for (int st = 0; st < 4; ++st) {
      float bv[2][4];
#pragma unroll
      for (int c = 0; c < 2; ++c)
#pragma unroll
        for (int r = 0; r < 4; ++r)
          bv[c][r] = bbase[(size_t)(st * 16 + g * 4 + r) * 2048 + kt +
                           c * 16 + r16];

      f32x4 sc[2];
#pragma unroll
      for (int c = 0; c < 2; ++c) {
        f32x4 z = {0.f, 0.f, 0.f, 0.f};
        f32x4 t =
            __builtin_amdgcn_mfma_f32_16x16x32_bf16(qf0[st], ka[c], z, 0, 0, 0);
        sc[c] =
            __builtin_amdgcn_mfma_f32_16x16x32_bf16(qf1[st], kc[c], t, 0, 0, 0);
      }
#pragma unroll
      for (int c = 0; c < 2; ++c)
#pragma unroll
        for (int r = 0; r < 4; ++r)
          sc[c][r] += bv[c][r];

      float mnew[4], rs[4];
#pragma unroll
      for (int r = 0; r < 4; ++r) {
        float t = fmaxf(sc[0][r], sc[1][r]);
        t = fmaxf(t, __shfl_xor(t, 1));
        t = fmaxf(t, __shfl_xor(t, 2));
        t = fmaxf(t, __shfl_xor(t, 4));
        t = fmaxf(t, __shfl_xor(t, 8));
        mnew[r] = fmaxf(m[st][r], t);
      }
#pragma unroll
      for (int r = 0; r < 4; ++r) {
        float p0 = __expf(sc[0][r] - mnew[r]);
        float p1 = __expf(sc[1][r] - mnew[r]);
        sc[0][r] = p0; sc[1][r] = p1;
        float t = p0 + p1;
        t += __shfl_xor(t, 1);
        t += __shfl_xor(t, 2);
        t += __shfl_xor(t, 4);
        t += __shfl_xor(t, 8);
        rs[r] = t;
        float alpha = __expf(m[st][r] - mnew[r]);
        lsum[st][r] = lsum[st][r] * alpha + rs[r];
        m[st][r] = mnew[r];
#pragma unroll
        for (int nt = 0; nt < 4; ++nt) acc[st][nt][r] *= alpha;
      }
#pragma unroll
      for (int c = 0; c < 2; ++c)
#pragma unroll
        for (int r = 0; r < 4; ++r)
          P_lds[w][(g * 4 + r) * 32 + c * 16 + r16] = f2bf(sc[c][r]);
      bf16x8 pf = ldb8(&P_lds[w][r16 * 32 + g * 8]);
#pragma unroll
      for (int nt = 0; nt < 4; ++nt)
        acc[st][nt] = __builtin_amdgcn_mfma_f32_16x16x32_bf16(
            pf, vf[nt], acc[st][nt], 0, 0, 0);
    }
  }

#pragma unroll
  for (int st = 0; st < 4; ++st) {
    __syncthreads();
#pragma unroll
    for (int nt = 0; nt < 4; ++nt)
#pragma unroll
      for (int r = 0; r < 4; ++r)
        acc_s[w][g * 4 + r][nt * 16 + r16] = acc[st][nt][r];
    if (r16 == 0) {
#pragma unroll
      for (int r = 0; r < 4; ++r) {
        m_s[w][g * 4 + r] = m[st][r];
        l_s[w][g * 4 + r] = lsum[st][r];
      }
    }
    __syncthreads();

    const int row = tid >> 4;
    const int col4 = (tid & 15) * 4;
    float m0v = m_s[0][row], m1v = m_s[1][row], m2v = m_s[2][row],
          m3v = m_s[3][row];
    float mm = fmaxf(fmaxf(m0v, m1v), fmaxf(m2v, m3v));
    float s0 = __expf(m0v - mm), s1 = __expf(m1v - mm);
    float s2 = __expf(m2v - mm), s3 = __expf(m3v - mm);
    float ltot = l_s[0][row] * s0 + l_s[1][row] * s1 + l_s[2][row] * s2 +
                 l_s[3][row] * s3;
    float inv = 1.f / ltot;
    ushort4 ov;
    u16* outp =
        attnb + (size_t)(qt * 64 + st * 16 + row) * 1024 + h * 64 + col4;
#pragma unroll
    for (int j = 0; j < 4; ++j) {
      float v = acc_s[0][row][col4 + j] * s0 + acc_s[1][row][col4 + j] * s1 +
                acc_s[2][row][col4 + j] * s2 + acc_s[3][row][col4 + j] * s3;
      ((u16*)&ov)[j] = f2bf(v * inv);
    }
    *(ushort4*)outp = ov;
  }
}

// ---------------- residual add + RMSNorm ----------------------------------
__global__ __launch_bounds__(256) void addnorm_kernel(
    const float* __restrict__ resid, const u16* __restrict__ delta,
    float* __restrict__ outf, u16* __restrict__ outb) {
  int row = blockIdx.x, tid = threadIdx.x;
  size_t base = (size_t)row * 1024 + tid * 4;
  float4 rv = *(const float4*)(resid + base);
  ushort4 dv = *(const ushort4*)(delta + base);
  float x0 = rv.x + bf2f(dv.x);
  float x1 = rv.y + bf2f(dv.y);
  float x2 = rv.z + bf2f(dv.z);
  float x3 = rv.w + bf2f(dv.w);
  float ss = x0 * x0 + x1 * x1 + x2 * x2 + x3 * x3;
#pragma unroll
  for (int sh = 32; sh >= 1; sh >>= 1) ss += __shfl_xor(ss, sh);
  __shared__ float red[4];
  if ((tid & 63) == 0) red[tid >> 6] = ss;
  __syncthreads();
  float tot = red[0] + red[1] + red[2] + red[3];
  float rstd = rsqrtf(tot * (1.0f / 1024.0f) + 1e-5f);
  float4 ov;
  ov.x = x0 * rstd; ov.y = x1 * rstd; ov.z = x2 * rstd; ov.w = x3 * rstd;
  *(float4*)(outf + base) = ov;
  if (outb) {
    ushort4 ob;
    ob.x = f2bf(ov.x); ob.y = f2bf(ov.y); ob.z = f2bf(ov.z); ob.w = f2bf(ov.w);
    *(ushort4*)(outb + base) = ob;
  }
}

extern "C" void kernel_launch(void* const* d_in, const int* in_sizes, int n_in,
                              void* d_out, int out_size, void* d_ws,
                              size_t ws_size, hipStream_t stream) {
  (void)in_sizes; (void)n_in; (void)out_size; (void)ws_size;
  const float* cosb  = (const float*)d_in[0];
  const float* sinb  = (const float*)d_in[1];
  const float* hidden = (const float*)d_in[2];
  const float* bias  = (const float*)d_in[3];
  const float* w_qkv = (const float*)d_in[4];
  const float* w_o   = (const float*)d_in[5];
  const float* w_gu  = (const float*)d_in[6];
  const float* w_down = (const float*)d_in[7];
  float* out = (float*)d_out;

  char* p = (char*)d_ws;
  auto alloc = [&](size_t bytes) {
    void* r = (void*)p;
    p += (bytes + 255) & ~(size_t)255;
    return r;
  };
  u16* wqkv_t = (u16*)alloc((size_t)3072 * 1024 * 2);
  u16* wo_t   = (u16*)alloc((size_t)1024 * 1024 * 2);
  u16* wgu_t  = (u16*)alloc((size_t)5632 * 1024 * 2);
  u16* wd_t   = (u16*)alloc((size_t)1024 * 2816 * 2);
  u16* xb     = (u16*)alloc((size_t)2048 * 1024 * 2);
  u16* qkvb   = (u16*)alloc((size_t)2048 * 3072 * 2);
  u16* qb     = (u16*)alloc((size_t)16 * 2048 * 64 * 2);
  u16* kb     = (u16*)alloc((size_t)16 * 2048 * 64 * 2);
  u16* vt     = (u16*)alloc((size_t)16 * 2048 * 64 * 2);
  u16* attnb  = (u16*)alloc((size_t)2048 * 1024 * 2);
  u16* ob     = (u16*)alloc((size_t)2048 * 1024 * 2);
  float* x1f  = (float*)alloc((size_t)2048 * 1024 * 4);
  u16* x1b    = (u16*)alloc((size_t)2048 * 1024 * 2);
  u16* hb     = (u16*)alloc((size_t)2048 * 2816 * 2);
  u16* mlpb   = (u16*)alloc((size_t)2048 * 1024 * 2);

  prep_kernel<<<14592, 256, 0, stream>>>(w_qkv, w_o, w_gu, w_down, hidden,
                                         wqkv_t, wo_t, wgu_t, wd_t, xb);

  gemm_bt<<<dim3(3072 / 128, 2048 / 128), 256, 0, stream>>>(xb, wqkv_t, qkvb, 2048, 3072, 1024);
  rope_kernel<<<dim3(64, 16), 256, 0, stream>>>(qkvb, cosb, sinb, qb, kb, vt);
  attn_kernel<<<512, 256, 0, stream>>>(qb, kb, vt, bias, attnb);
  gemm_bt64<<<dim3(1024 / 128, 2048 / 64), 256, 0, stream>>>(attnb, wo_t, ob, 2048, 1024, 1024);
  addnorm_kernel<<<2048, 256, 0, stream>>>(hidden, ob, x1f, x1b);
  gemm_bt_swiglu<<<dim3(5632 / 128, 2048 / 128), 256, 0, stream>>>(x1b, wgu_t, hb, 2048, 5632, 1024);
  gemm_bt64<<<dim3(1024 / 128, 2048 / 64), 256, 0, stream>>>(hb, wd_t, mlpb, 2048, 1024, 2816);
  addnorm_kernel<<<2048, 256, 0, stream>>>(x1f, mlpb, out, nullptr);
}

// Round 15
// 288.576 us; speedup vs baseline: 1.1516x; 1.0738x over previous
//
#include <hip/hip_runtime.h>
#include <stdint.h>

using u16 = unsigned short;
typedef __bf16 bf16x8 __attribute__((ext_vector_type(8)));
typedef float f32x4 __attribute__((ext_vector_type(4)));

__device__ __forceinline__ u16 f2bf(float f) {
  union { float f; uint32_t u; } v; v.f = f;
  uint32_t r = v.u + 0x7fffu + ((v.u >> 16) & 1u);
  return (u16)(r >> 16);
}
__device__ __forceinline__ float bf2f(u16 h) {
  union { uint32_t u; float f; } v; v.u = ((uint32_t)h) << 16;
  return v.f;
}
__device__ __forceinline__ bf16x8 ldb8(const u16* p) {
  return *reinterpret_cast<const bf16x8*>(p);
}
__device__ __forceinline__ void gload_lds16(const void* g, void* l) {
  __builtin_amdgcn_global_load_lds(
      (const __attribute__((address_space(1))) void*)g,
      (__attribute__((address_space(3))) void*)l, 16, 0, 0);
}

// ---------------- fused prep: f32->bf16 convert + 4 weight transposes -----
__global__ __launch_bounds__(256) void prep_kernel(
    const float* __restrict__ w_qkv, const float* __restrict__ w_o,
    const float* __restrict__ w_gu, const float* __restrict__ w_down,
    const float* __restrict__ hidden, u16* __restrict__ wqkv_t,
    u16* __restrict__ wo_t, u16* __restrict__ wgu_t, u16* __restrict__ wd_t,
    u16* __restrict__ xb) {
  const int b = blockIdx.x;
  const int t = threadIdx.x;

  if (b >= 12544) {  // convert job
    int idx = (b - 12544) * 256 + t;
    float4 v = *(const float4*)(hidden + (size_t)idx * 4);
    ushort4 o;
    o.x = f2bf(v.x); o.y = f2bf(v.y); o.z = f2bf(v.z); o.w = f2bf(v.w);
    *(ushort4*)(xb + (size_t)idx * 4) = o;
    return;
  }

  const float* W;
  u16* Wt;
  int N, K, lb;
  bool perm = false;
  if (b < 3072)      { W = w_qkv; Wt = wqkv_t; N = 3072; K = 1024; lb = b; }
  else if (b < 4096) { W = w_o;   Wt = wo_t;   N = 1024; K = 1024; lb = b - 3072; }
  else if (b < 9728) { W = w_gu;  Wt = wgu_t;  N = 5632; K = 1024; lb = b - 4096; perm = true; }
  else               { W = w_down; Wt = wd_t;  N = 1024; K = 2816; lb = b - 9728; }

  const int nx = N >> 5;
  const int n0 = (lb % nx) * 32, k0 = (lb / nx) * 32;
  const int tx = t & 31, ty = t >> 5;  // (32, 8)

  __shared__ u16 tile[32][33];
  const int nc = n0 + tx;
  const int src_col = perm ? (((nc & 1) == 0) ? (nc >> 1) : 2816 + (nc >> 1))
                           : nc;
#pragma unroll
  for (int i = 0; i < 32; i += 8)
    tile[ty + i][tx] = f2bf(W[(size_t)(k0 + ty + i) * N + src_col]);
  __syncthreads();
#pragma unroll
  for (int i = 0; i < 32; i += 8)
    Wt[(size_t)(n0 + ty + i) * K + k0 + tx] = tile[tx][ty + i];
}

// ---------------- GEMM 128x128 + fused RoPE/V-transpose epilogue ----------
// qkv GEMM only (N=3072). A 128-col tile = 2 complete heads of one type
// (cols [0,1024)=q heads, [1024,2048)=k, [2048,3072)=v). Epilogue:
//  q/k: rope in registers -- pair d<->d^32 is acc fragment nt<->nt^2 in the
//       SAME lane; q additionally scaled by 0.125 (score scale fold).
//       Single rounding (fp32 acc -> bf16), vs double in the old path.
//  v:   64x64 wave tile transposed via per-wave LDS slice (same-wave
//       write->read, R6-proven), written to vt[h][d][s] in 32B s-runs.
// No C write -- qkvb buffer eliminated.
__global__ __launch_bounds__(256) void gemm_qkv_rope(
    const u16* __restrict__ A, const u16* __restrict__ Bt,
    const float* __restrict__ cosb, const float* __restrict__ sinb,
    u16* __restrict__ qb, u16* __restrict__ kb, u16* __restrict__ vt,
    int M, int N, int K) {
  __shared__ __align__(16) u16 As[128 * 32];
  __shared__ __align__(16) u16 Bs[128 * 32];
  __shared__ u16 vbuf[4][64][17];
  const int tid = threadIdx.x;
  const int w = tid >> 6, lane = tid & 63;
  const int wr = w >> 1, wc = w & 1;
  const int r16 = lane & 15, g = lane >> 4;
  const int nwg = gridDim.x * gridDim.y;
  const int idx = blockIdx.y * gridDim.x + blockIdx.x;
  const int swz = (idx & 7) * (nwg >> 3) + (idx >> 3);  // bijective, nwg%8==0
  const int m0 = (swz / gridDim.x) * 128, n0 = (swz % gridDim.x) * 128;
  const int ldrow = lane >> 2;
  const int ldk = (lane & 3) * 8;

  f32x4 acc[4][4] = {};

  for (int kt = 0; kt < K; kt += 32) {
#pragma unroll
    for (int i = 0; i < 2; ++i) {
      int chunk = w * 2 + i;
      int row = chunk * 16 + ldrow;
      gload_lds16(A + (size_t)(m0 + row) * K + kt + ldk, &As[chunk * 512]);
      gload_lds16(Bt + (size_t)(n0 + row) * K + kt + ldk, &Bs[chunk * 512]);
    }
    __syncthreads();
    bf16x8 a[4], b[4];
#pragma unroll
    for (int mt = 0; mt < 4; ++mt)
      a[mt] = ldb8(&As[(wr * 64 + mt * 16 + r16) * 32 + g * 8]);
#pragma unroll
    for (int nt = 0; nt < 4; ++nt)
      b[nt] = ldb8(&Bs[(wc * 64 + nt * 16 + r16) * 32 + g * 8]);
#pragma unroll
    for (int mt = 0; mt < 4; ++mt)
#pragma unroll
      for (int nt = 0; nt < 4; ++nt)
        acc[mt][nt] = __builtin_amdgcn_mfma_f32_16x16x32_bf16(
            a[mt], b[nt], acc[mt][nt], 0, 0, 0);
    __syncthreads();
  }

  const int type = n0 >> 10;                  // 0=q, 1=k, 2=v
  const int head = ((n0 & 1023) >> 6) + wc;   // 2 heads per tile, wc picks
  if (type < 2) {
    u16* outp = type == 0 ? qb : kb;
    const float qs = type == 0 ? 0.125f : 1.0f;
#pragma unroll
    for (int mt = 0; mt < 4; ++mt)
#pragma unroll
      for (int r = 0; r < 4; ++r) {
        const int srow = m0 + wr * 64 + mt * 16 + g * 4 + r;
#pragma unroll
        for (int nt = 0; nt < 4; ++nt) {
          const int d = nt * 16 + r16;
          float cv = cosb[srow * 64 + d];
          float sv = sinb[srow * 64 + d];
          float sgn = nt < 2 ? -1.f : 1.f;  // d<32 -> -x[d+32], else +x[d-32]
          float val = acc[mt][nt][r] * cv + sgn * acc[mt][nt ^ 2][r] * sv;
          outp[((size_t)head * 2048 + srow) * 64 + d] = f2bf(val * qs);
        }
      }
  } else {
    const int s_base = m0 + wr * 64;
    const int d_lo = lane >> 4;        // placeholder, real below
    (void)d_lo;
    const int dl = lane >> 2;          // 0..15: d within 16-chunk
    const int sblk = (lane & 3) * 16;  // 0,16,32,48: s sub-block
#pragma unroll
    for (int nt = 0; nt < 4; ++nt) {
#pragma unroll
      for (int mt = 0; mt < 4; ++mt)
#pragma unroll
        for (int r = 0; r < 4; ++r)
          vbuf[w][mt * 16 + g * 4 + r][r16] = f2bf(acc[mt][nt][r]);
      // same-wave LDS write -> cross-lane read (program order preserved)
      u16* dst =
          vt + ((size_t)(head * 64 + nt * 16 + dl)) * 2048 + s_base + sblk;
#pragma unroll
      for (int jj = 0; jj < 4; ++jj) {
        ushort4 ov;
        ov.x = vbuf[w][sblk + jj * 4 + 0][dl];
        ov.y = vbuf[w][sblk + jj * 4 + 1][dl];
        ov.z = vbuf[w][sblk + jj * 4 + 2][dl];
        ov.w = vbuf[w][sblk + jj * 4 + 3][dl];
        *(ushort4*)(dst + jj * 4) = ov;
      }
    }
  }
}

// ---------------- GEMM 128x128 + fused SwiGLU epilogue --------------------
__global__ __launch_bounds__(256) void gemm_bt_swiglu(
    const u16* __restrict__ A, const u16* __restrict__ Bt,
    u16* __restrict__ Hb, int M, int N, int K) {
  __shared__ __align__(16) u16 As[128 * 32];
  __shared__ __align__(16) u16 Bs[128 * 32];
  const int tid = threadIdx.x;
  const int w = tid >> 6, lane = tid & 63;
  const int wr = w >> 1, wc = w & 1;
  const int r16 = lane & 15, g = lane >> 4;
  const int nwg = gridDim.x * gridDim.y;
  const int idx = blockIdx.y * gridDim.x + blockIdx.x;
  const int swz = (idx & 7) * (nwg >> 3) + (idx >> 3);
  const int m0 = (swz / gridDim.x) * 128, n0 = (swz % gridDim.x) * 128;
  const int ldrow = lane >> 2;
  const int ldk = (lane & 3) * 8;

  f32x4 acc[4][4] = {};

  for (int kt = 0; kt < K; kt += 32) {
#pragma unroll
    for (int i = 0; i < 2; ++i) {
      int chunk = w * 2 + i;
      int row = chunk * 16 + ldrow;
      gload_lds16(A + (size_t)(m0 + row) * K + kt + ldk, &As[chunk * 512]);
      gload_lds16(Bt + (size_t)(n0 + row) * K + kt + ldk, &Bs[chunk * 512]);
    }
    __syncthreads();
    bf16x8 a[4], b[4];
#pragma unroll
    for (int mt = 0; mt < 4; ++mt)
      a[mt] = ldb8(&As[(wr * 64 + mt * 16 + r16) * 32 + g * 8]);
#pragma unroll
    for (int nt = 0; nt < 4; ++nt)
      b[nt] = ldb8(&Bs[(wc * 64 + nt * 16 + r16) * 32 + g * 8]);
#pragma unroll
    for (int mt = 0; mt < 4; ++mt)
#pragma unroll
      for (int nt = 0; nt < 4; ++nt)
        acc[mt][nt] = __builtin_amdgcn_mfma_f32_16x16x32_bf16(
            a[mt], b[nt], acc[mt][nt], 0, 0, 0);
    __syncthreads();
  }
#pragma unroll
  for (int mt = 0; mt < 4; ++mt)
#pragma unroll
    for (int nt = 0; nt < 4; ++nt)
#pragma unroll
      for (int r = 0; r < 4; ++r) {
        float val = acc[mt][nt][r];
        float other = __shfl_xor(val, 1);  // all lanes participate
        if ((r16 & 1) == 0) {
          float o = val / (1.f + __expf(-val)) * other;  // silu(gate)*up
          int row = m0 + wr * 64 + mt * 16 + g * 4 + r;
          int col = n0 + wc * 64 + nt * 16 + r16;
          Hb[(size_t)row * 2816 + (col >> 1)] = f2bf(o);
        }
      }
}

// ---------------- GEMM 64x128 (R12-exact, XCD-swizzled) -------------------
__global__ __launch_bounds__(256) void gemm_bt64(
    const u16* __restrict__ A, const u16* __restrict__ Bt,
    u16* __restrict__ C, int M, int N, int K) {
  __shared__ __align__(16) u16 As[64 * 32];
  __shared__ __align__(16) u16 Bs[128 * 32];
  const int tid = threadIdx.x;
  const int w = tid >> 6, lane = tid & 63;
  const int wr = w >> 1, wc = w & 1;
  const int r16 = lane & 15, g = lane >> 4;
  const int nwg = gridDim.x * gridDim.y;
  const int idx = blockIdx.y * gridDim.x + blockIdx.x;
  const int swz = (idx & 7) * (nwg >> 3) + (idx >> 3);  // bijective, nwg%8==0
  const int m0 = (swz / gridDim.x) * 64, n0 = (swz % gridDim.x) * 128;
  const int ldrow = lane >> 2;
  const int ldk = (lane & 3) * 8;

  f32x4 acc[2][4] = {};

  for (int kt = 0; kt < K; kt += 32) {
#pragma unroll
    for (int i = 0; i < 3; ++i) {
      int chunk = w * 3 + i;  // 0..11: 0-3 -> A, 4-11 -> B
      if (chunk < 4) {
        int row = chunk * 16 + ldrow;
        gload_lds16(A + (size_t)(m0 + row) * K + kt + ldk, &As[chunk * 512]);
      } else {
        int cb = chunk - 4;
        int row = cb * 16 + ldrow;
        gload_lds16(Bt + (size_t)(n0 + row) * K + kt + ldk, &Bs[cb * 512]);
      }
    }
    __syncthreads();
    bf16x8 a[2], b[4];
#pragma unroll
    for (int mt = 0; mt < 2; ++mt)
      a[mt] = ldb8(&As[(wr * 32 + mt * 16 + r16) * 32 + g * 8]);
#pragma unroll
    for (int nt = 0; nt < 4; ++nt)
      b[nt] = ldb8(&Bs[(wc * 64 + nt * 16 + r16) * 32 + g * 8]);
#pragma unroll
    for (int mt = 0; mt < 2; ++mt)
#pragma unroll
      for (int nt = 0; nt < 4; ++nt)
        acc[mt][nt] = __builtin_amdgcn_mfma_f32_16x16x32_bf16(
            a[mt], b[nt], acc[mt][nt], 0, 0, 0);
    __syncthreads();
  }
#pragma unroll
  for (int mt = 0; mt < 2; ++mt)
#pragma unroll
    for (int nt = 0; nt < 4; ++nt)
#pragma unroll
      for (int r = 0; r < 4; ++r) {
        int row = m0 + wr * 32 + mt * 16 + g * 4 + r;
        int col = n0 + wc * 64 + nt * 16 + r16;
        C[(size_t)row * N + col] = f2bf(acc[mt][nt][r]);
      }
}

// ---------------- flash attention (R9 structure, per-lane lsum) -----------
// Only change vs R14: the per-step cross-lane SUM reduction is deferred --
// lsum is per-lane (lp = lp*alpha + p0+p1; alpha is row-uniform, so this is
// algebraically exact) and reduced once per subtile at the end. Max chain,
// rescale, and combine are byte-identical.
__global__ __launch_bounds__(256, 2) void attn_kernel(
    const u16* __restrict__ qb, const u16* __restrict__ kb,
    const u16* __restrict__ vt, const float* __restrict__ bias,
    u16* __restrict__ attnb) {
  const int bid = blockIdx.x;
  const int swz = (bid & 7) * 64 + (bid >> 3);
  const int h = swz >> 5;
  const int qt = swz & 31;
  const int tid = threadIdx.x;
  const int w = tid >> 6;
  const int lane = tid & 63;
  const int r16 = lane & 15, g = lane >> 4;

  __shared__ __align__(16) u16 P_lds[4][16 * 32];
  __shared__ float acc_s[4][16][64];
  __shared__ float m_s[4][16], l_s[4][16];

  bf16x8 qf0[4], qf1[4];
#pragma unroll
  for (int st = 0; st < 4; ++st) {
    const u16* qrow =
        qb + ((size_t)h * 2048 + qt * 64 + st * 16 + r16) * 64;
    qf0[st] = ldb8(qrow + g * 8);
    qf1[st] = ldb8(qrow + 32 + g * 8);
  }

  f32x4 acc[4][4] = {};
  float m[4][4], lsum[4][4];
#pragma unroll
  for (int st = 0; st < 4; ++st)
#pragma unroll
    for (int r = 0; r < 4; ++r) { m[st][r] = -1e30f; lsum[st][r] = 0.f; }

  const float* bbase = bias + ((size_t)h * 2048 + qt * 64) * 2048;

  const int kv0 = w * 512, kv1 = kv0 + 512;
  for (int kt = kv0; kt < kv1; kt += 32) {
    bf16x8 ka[2], kc[2];
#pragma unroll
    for (int c = 0; c < 2; ++c) {
      const u16* krow = kb + ((size_t)h * 2048 + kt + c * 16 + r16) * 64;
      ka[c] = ldb8(krow + g * 8);
      kc[c] = ldb8(krow + 32 + g * 8);
    }
    bf16x8 vf[4];
#pragma unroll
    for (int nt = 0; nt < 4; ++nt)
      vf[nt] =
          ldb8(vt + ((size_t)h * 64 + nt * 16 + r16) * 2048 + kt + g * 8);

#pragma unroll
    for (int st = 0; st < 4; ++st) {
      float bv[2][4];
#pragma unroll
      for (int c = 0; c < 2; ++c)
#pragma unroll
        for (int r = 0; r < 4; ++r)
          bv[c][r] = bbase[(size_t)(st * 16 + g * 4 + r) * 2048 + kt +
                           c * 16 + r16];

      f32x4 sc[2];
#pragma unroll
      for (int c = 0; c < 2; ++c) {
        f32x4 z = {0.f, 0.f, 0.f, 0.f};
        f32x4 t =
            __builtin_amdgcn_mfma_f32_16x16x32_bf16(qf0[st], ka[c], z, 0, 0, 0);
        sc[c] =
            __builtin_amdgcn_mfma_f32_16x16x32_bf16(qf1[st], kc[c], t, 0, 0, 0);
      }
#pragma unroll
      for (int c = 0; c < 2; ++c)
#pragma unroll
        for (int r = 0; r < 4; ++r)
          sc[c][r] += bv[c][r];

      float mnew[4];
#pragma unroll
      for (int r = 0; r < 4; ++r) {
        float t = fmaxf(sc[0][r], sc[1][r]);
        t = fmaxf(t, __shfl_xor(t, 1));
        t = fmaxf(t, __shfl_xor(t, 2));
        t = fmaxf(t, __shfl_xor(t, 4));
        t = fmaxf(t, __shfl_xor(t, 8));
        mnew[r] = fmaxf(m[st][r], t);
      }
#pragma unroll
      for (int r = 0; r < 4; ++r) {
        float p0 = __expf(sc[0][r] - mnew[r]);
        float p1 = __expf(sc[1][r] - mnew[r]);
        sc[0][r] = p0; sc[1][r] = p1;
        float alpha = __expf(m[st][r] - mnew[r]);
        lsum[st][r] = lsum[st][r] * alpha + (p0 + p1);  // per-lane partial
        m[st][r] = mnew[r];
#pragma unroll
        for (int nt = 0; nt < 4; ++nt) acc[st][nt][r] *= alpha;
      }
#pragma unroll
      for (int c = 0; c < 2; ++c)
#pragma unroll
        for (int r = 0; r < 4; ++r)
          P_lds[w][(g * 4 + r) * 32 + c * 16 + r16] = f2bf(sc[c][r]);
      bf16x8 pf = ldb8(&P_lds[w][r16 * 32 + g * 8]);
#pragma unroll
      for (int nt = 0; nt < 4; ++nt)
        acc[st][nt] = __builtin_amdgcn_mfma_f32_16x16x32_bf16(
            pf, vf[nt], acc[st][nt], 0, 0, 0);
    }
  }

#pragma unroll
  for (int st = 0; st < 4; ++st) {
    __syncthreads();
#pragma unroll
    for (int nt = 0; nt < 4; ++nt)
#pragma unroll
      for (int r = 0; r < 4; ++r)
        acc_s[w][g * 4 + r][nt * 16 + r16] = acc[st][nt][r];
    if (r16 == 0) {
#pragma unroll
      for (int r = 0; r < 4; ++r) m_s[w][g * 4 + r] = m[st][r];
    }
#pragma unroll
    for (int r = 0; r < 4; ++r) {  // deferred row-sum of lsum
      float t = lsum[st][r];
      t += __shfl_xor(t, 1);
      t += __shfl_xor(t, 2);
      t += __shfl_xor(t, 4);
      t += __shfl_xor(t, 8);
      if (r16 == 0) l_s[w][g * 4 + r] = t;
    }
    __syncthreads();

    const int row = tid >> 4;
    const int col4 = (tid & 15) * 4;
    float m0v = m_s[0][row], m1v = m_s[1][row], m2v = m_s[2][row],
          m3v = m_s[3][row];
    float mm = fmaxf(fmaxf(m0v, m1v), fmaxf(m2v, m3v));
    float s0 = __expf(m0v - mm), s1 = __expf(m1v - mm);
    float s2 = __expf(m2v - mm), s3 = __expf(m3v - mm);
    float ltot = l_s[0][row] * s0 + l_s[1][row] * s1 + l_s[2][row] * s2 +
                 l_s[3][row] * s3;
    float inv = 1.f / ltot;
    ushort4 ov;
    u16* outp =
        attnb + (size_t)(qt * 64 + st * 16 + row) * 1024 + h * 64 + col4;
#pragma unroll
    for (int j = 0; j < 4; ++j) {
      float v = acc_s[0][row][col4 + j] * s0 + acc_s[1][row][col4 + j] * s1 +
                acc_s[2][row][col4 + j] * s2 + acc_s[3][row][col4 + j] * s3;
      ((u16*)&ov)[j] = f2bf(v * inv);
    }
    *(ushort4*)outp = ov;
  }
}

// ---------------- residual add + RMSNorm ----------------------------------
__global__ __launch_bounds__(256) void addnorm_kernel(
    const float* __restrict__ resid, const u16* __restrict__ delta,
    float* __restrict__ outf, u16* __restrict__ outb) {
  int row = blockIdx.x, tid = threadIdx.x;
  size_t base = (size_t)row * 1024 + tid * 4;
  float4 rv = *(const float4*)(resid + base);
  ushort4 dv = *(const ushort4*)(delta + base);
  float x0 = rv.x + bf2f(dv.x);
  float x1 = rv.y + bf2f(dv.y);
  float x2 = rv.z + bf2f(dv.z);
  float x3 = rv.w + bf2f(dv.w);
  float ss = x0 * x0 + x1 * x1 + x2 * x2 + x3 * x3;
#pragma unroll
  for (int sh = 32; sh >= 1; sh >>= 1) ss += __shfl_xor(ss, sh);
  __shared__ float red[4];
  if ((tid & 63) == 0) red[tid >> 6] = ss;
  __syncthreads();
  float tot = red[0] + red[1] + red[2] + red[3];
  float rstd = rsqrtf(tot * (1.0f / 1024.0f) + 1e-5f);
  float4 ov;
  ov.x = x0 * rstd; ov.y = x1 * rstd; ov.z = x2 * rstd; ov.w = x3 * rstd;
  *(float4*)(outf + base) = ov;
  if (outb) {
    ushort4 ob;
    ob.x = f2bf(ov.x); ob.y = f2bf(ov.y); ob.z = f2bf(ov.z); ob.w = f2bf(ov.w);
    *(ushort4*)(outb + base) = ob;
  }
}

extern "C" void kernel_launch(void* const* d_in, const int* in_sizes, int n_in,
                              void* d_out, int out_size, void* d_ws,
                              size_t ws_size, hipStream_t stream) {
  (void)in_sizes; (void)n_in; (void)out_size; (void)ws_size;
  const float* cosb  = (const float*)d_in[0];
  const float* sinb  = (const float*)d_in[1];
  const float* hidden = (const float*)d_in[2];
  const float* bias  = (const float*)d_in[3];
  const float* w_qkv = (const float*)d_in[4];
  const float* w_o   = (const float*)d_in[5];
  const float* w_gu  = (const float*)d_in[6];
  const float* w_down = (const float*)d_in[7];
  float* out = (float*)d_out;

  char* p = (char*)d_ws;
  auto alloc = [&](size_t bytes) {
    void* r = (void*)p;
    p += (bytes + 255) & ~(size_t)255;
    return r;
  };
  u16* wqkv_t = (u16*)alloc((size_t)3072 * 1024 * 2);
  u16* wo_t   = (u16*)alloc((size_t)1024 * 1024 * 2);
  u16* wgu_t  = (u16*)alloc((size_t)5632 * 1024 * 2);
  u16* wd_t   = (u16*)alloc((size_t)1024 * 2816 * 2);
  u16* xb     = (u16*)alloc((size_t)2048 * 1024 * 2);
  u16* qb     = (u16*)alloc((size_t)16 * 2048 * 64 * 2);
  u16* kb     = (u16*)alloc((size_t)16 * 2048 * 64 * 2);
  u16* vt     = (u16*)alloc((size_t)16 * 2048 * 64 * 2);
  u16* attnb  = (u16*)alloc((size_t)2048 * 1024 * 2);
  u16* ob     = (u16*)alloc((size_t)2048 * 1024 * 2);
  float* x1f  = (float*)alloc((size_t)2048 * 1024 * 4);
  u16* x1b    = (u16*)alloc((size_t)2048 * 1024 * 2);
  u16* hb     = (u16*)alloc((size_t)2048 * 2816 * 2);
  u16* mlpb   = (u16*)alloc((size_t)2048 * 1024 * 2);

  prep_kernel<<<14592, 256, 0, stream>>>(w_qkv, w_o, w_gu, w_down, hidden,
                                         wqkv_t, wo_t, wgu_t, wd_t, xb);

  gemm_qkv_rope<<<dim3(3072 / 128, 2048 / 128), 256, 0, stream>>>(
      xb, wqkv_t, cosb, sinb, qb, kb, vt, 2048, 3072, 1024);
  attn_kernel<<<512, 256, 0, stream>>>(qb, kb, vt, bias, attnb);
  gemm_bt64<<<dim3(1024 / 128, 2048 / 64), 256, 0, stream>>>(attnb, wo_t, ob, 2048, 1024, 1024);
  addnorm_kernel<<<2048, 256, 0, stream>>>(hidden, ob, x1f, x1b);
  gemm_bt_swiglu<<<dim3(5632 / 128, 2048 / 128), 256, 0, stream>>>(x1b, wgu_t, hb, 2048, 5632, 1024);
  gemm_bt64<<<dim3(1024 / 128, 2048 / 64), 256, 0, stream>>>(hb, wd_t, mlpb, 2048, 1024, 2816);
  addnorm_kernel<<<2048, 256, 0, stream>>>(x1f, mlpb, out, nullptr);
}